// Round 9
// baseline (276.373 us; speedup 1.0000x reference)
//
#include <hip/hip_runtime.h>

#define N_PTS  (4*1024*1024)
#define NCLUST 65536

// ---------------------------------------------------------------------------
// Kernel 0: zero-fill pooled (ws is re-poisoned 0xAA before every launch).
// ---------------------------------------------------------------------------
__global__ __launch_bounds__(256) void k_zero(float4* __restrict__ p)
{
    p[(size_t)blockIdx.x * 256 + threadIdx.x] = make_float4(0.f, 0.f, 0.f, 0.f);
}

// ---------------------------------------------------------------------------
// Kernel 1: fc0 (3->64) + ReLU + sorted segment-max pool. (R7, unchanged)
// Wave = 64 lanes = 64 features; wave owns 256 points in 4 rounds of 64.
// Points staged into lanes (coalesced 12B/lane), broadcast via v_readlane
// (VALU pipe — not LDS, not K$). Run change -> ONE atomicMax instruction.
// ---------------------------------------------------------------------------
__global__ __launch_bounds__(256) void k_fc0_pool(
        const float* __restrict__ pts,          // [N,3]
        const int* __restrict__ clus,           // [N] sorted int32, < NCLUST
        const float* __restrict__ W0,           // [3,64]
        const float* __restrict__ b0,           // [64]
        float* __restrict__ pooled)             // [NCLUST,64], pre-zeroed
{
    const int tid  = threadIdx.x;
    const int lane = tid & 63;
    const int w    = tid >> 6;
    const int base = blockIdx.x * 1024 + w * 256;

    const float w0x = W0[lane];
    const float w0y = W0[64 + lane];
    const float w0z = W0[128 + lane];
    const float bb  = b0[lane];

    unsigned* pool_u = (unsigned*)pooled;
    int   cur  = clus[base];
    float vmax = 0.0f;

#define FLUSH(RID) { \
    atomicMax(&pool_u[(size_t)(RID) * 64 + lane], __float_as_uint(vmax)); \
    vmax = 0.0f; }

#define RL_F(v, i) __uint_as_float(__builtin_amdgcn_readlane(__float_as_uint(v), (i)))

    #pragma unroll 1
    for (int rnd = 0; rnd < 4; ++rnd) {
        const int rb = base + rnd * 64;
        const float* ps = pts + (size_t)rb * 3;
        const float vx = ps[lane * 3 + 0];
        const float vy = ps[lane * 3 + 1];
        const float vz = ps[lane * 3 + 2];
        const int   vc = clus[rb + lane];

        #pragma unroll
        for (int ch = 0; ch < 4; ++ch) {
            const int i0 = ch * 16;
            const int cf = __builtin_amdgcn_readlane(vc, i0);
            const int cl = __builtin_amdgcn_readlane(vc, i0 + 15);
            if (cf == cl) {
                if (cf != cur) { FLUSH(cur); cur = cf; }
                float m0 = vmax, m1 = vmax, m2 = vmax, m3 = vmax;
                #pragma unroll
                for (int t = 0; t < 16; t += 4) {
                    const float ax = RL_F(vx, i0 + t),     ay = RL_F(vy, i0 + t),     az = RL_F(vz, i0 + t);
                    const float bx = RL_F(vx, i0 + t + 1), by = RL_F(vy, i0 + t + 1), bz = RL_F(vz, i0 + t + 1);
                    const float cx = RL_F(vx, i0 + t + 2), cy = RL_F(vy, i0 + t + 2), cz = RL_F(vz, i0 + t + 2);
                    const float dx = RL_F(vx, i0 + t + 3), dy = RL_F(vy, i0 + t + 3), dz = RL_F(vz, i0 + t + 3);
                    m0 = fmaxf(m0, fmaf(ax, w0x, fmaf(ay, w0y, fmaf(az, w0z, bb))));
                    m1 = fmaxf(m1, fmaf(bx, w0x, fmaf(by, w0y, fmaf(bz, w0z, bb))));
                    m2 = fmaxf(m2, fmaf(cx, w0x, fmaf(cy, w0y, fmaf(cz, w0z, bb))));
                    m3 = fmaxf(m3, fmaf(dx, w0x, fmaf(dy, w0y, fmaf(dz, w0z, bb))));
                }
                vmax = fmaxf(fmaxf(m0, m1), fmaxf(m2, m3));
            } else {
                #pragma unroll 1
                for (int t = 0; t < 16; ++t) {
                    const int c = __builtin_amdgcn_readlane(vc, i0 + t);
                    if (c != cur) { FLUSH(cur); cur = c; }
                    const float sx = RL_F(vx, i0 + t);
                    const float sy = RL_F(vy, i0 + t);
                    const float sz = RL_F(vz, i0 + t);
                    vmax = fmaxf(vmax, fmaf(sx, w0x, fmaf(sy, w0y, fmaf(sz, w0z, bb))));
                }
            }
        }
    }
    FLUSH(cur);
#undef FLUSH
#undef RL_F
}

// ---------------------------------------------------------------------------
// Kernel 2 (v2): fused fc1+fc2 — VECTOR-pipe weights + max occupancy.
// R7 post-mortem: scalar (K$) weight streaming convoys waves (VALUBusy 43%),
// LDS-transpose epilogue caused 1.7M bank conflicts. This version:
//  - block 256 thr / 16 rows (grid 4096); LDS = Ps 4KB + Hs 8.25KB = 12.3KB
//  - W1/W2 read per-lane as float4 from global (L1/L2-hot vector pipe,
//    lanes L and L+32 share addresses -> coalescer dedup; L1 absorbs the
//    4-way wave redundancy)
//  - h broadcast from LDS (wave-uniform addr); Hs padded 128->132
//  - per-thread tile sized for VGPR<=64 -> 8 waves/SIMD resident
//  - direct coalesced stores (one full 1KB row per wave-store), no transpose
// ---------------------------------------------------------------------------
__global__ __launch_bounds__(256, 8) void k_mlp(
        const float* __restrict__ pooled,
        const float* __restrict__ W1,
        const float* __restrict__ b1,
        const float* __restrict__ W2,
        const float* __restrict__ b2,
        float* __restrict__ out)
{
    __shared__ float Ps[16 * 64];
    __shared__ float Hs[16 * 132];

    const int tid = threadIdx.x;
    const int r0  = blockIdx.x * 16;

    // stage Ps[16][64] (256 float4, contiguous)
    ((float4*)Ps)[tid] = ((const float4*)(pooled + (size_t)r0 * 64))[tid];
    __syncthreads();

    // ---------------- Phase A: fc1  Ps[16,64] @ W1[64,128] -> Hs ----------
    {
        const int cq = tid & 31;          // col quad (128 cols)
        const int rg = tid >> 5;          // 8 groups x 2 rows
        const float4 bv = ((const float4*)b1)[cq];
        float acc[2][4];
        #pragma unroll
        for (int r = 0; r < 2; ++r) {
            acc[r][0] = bv.x; acc[r][1] = bv.y; acc[r][2] = bv.z; acc[r][3] = bv.w;
        }
        const float4* W1g = (const float4*)W1;   // [64][32]
        const float4* Ps4 = (const float4*)Ps;   // [16][16]
        #pragma unroll 4
        for (int k4 = 0; k4 < 16; ++k4) {
            float4 wv[4], pv[2];
            #pragma unroll
            for (int kk = 0; kk < 4; ++kk) wv[kk] = W1g[(k4 * 4 + kk) * 32 + cq];
            #pragma unroll
            for (int rr = 0; rr < 2; ++rr) pv[rr] = Ps4[(rg * 2 + rr) * 16 + k4];
            #pragma unroll
            for (int rr = 0; rr < 2; ++rr) {
                const float* p = (const float*)&pv[rr];
                #pragma unroll
                for (int kk = 0; kk < 4; ++kk) {
                    const float* wq = (const float*)&wv[kk];
                    acc[rr][0] = fmaf(p[kk], wq[0], acc[rr][0]);
                    acc[rr][1] = fmaf(p[kk], wq[1], acc[rr][1]);
                    acc[rr][2] = fmaf(p[kk], wq[2], acc[rr][2]);
                    acc[rr][3] = fmaf(p[kk], wq[3], acc[rr][3]);
                }
            }
        }
        #pragma unroll
        for (int rr = 0; rr < 2; ++rr) {
            float* d = &Hs[(rg * 2 + rr) * 132 + cq * 4];
            d[0] = fmaxf(acc[rr][0], 0.0f);
            d[1] = fmaxf(acc[rr][1], 0.0f);
            d[2] = fmaxf(acc[rr][2], 0.0f);
            d[3] = fmaxf(acc[rr][3], 0.0f);
        }
    }
    __syncthreads();

    // ---------------- Phase B: fc2  Hs[16,128] @ W2[128,256] -> out -------
    {
        const int cg = tid & 63;          // col quad (256 cols)
        const int rg = tid >> 6;          // 4 groups x 4 rows
        const float4 bv = ((const float4*)b2)[cg];
        float acc[4][4];
        #pragma unroll
        for (int r = 0; r < 4; ++r) {
            acc[r][0] = bv.x; acc[r][1] = bv.y; acc[r][2] = bv.z; acc[r][3] = bv.w;
        }
        const float4* W2g = (const float4*)W2;   // [128][64]
        #pragma unroll 2
        for (int k4 = 0; k4 < 32; ++k4) {
            float4 hv[4];
            #pragma unroll
            for (int rr = 0; rr < 4; ++rr)
                hv[rr] = *(const float4*)&Hs[(rg * 4 + rr) * 132 + k4 * 4];
            #pragma unroll
            for (int kk = 0; kk < 4; ++kk) {
                const float4 wv = W2g[(k4 * 4 + kk) * 64 + cg];
                #pragma unroll
                for (int rr = 0; rr < 4; ++rr) {
                    const float hk = ((const float*)&hv[rr])[kk];
                    acc[rr][0] = fmaf(hk, wv.x, acc[rr][0]);
                    acc[rr][1] = fmaf(hk, wv.y, acc[rr][1]);
                    acc[rr][2] = fmaf(hk, wv.z, acc[rr][2]);
                    acc[rr][3] = fmaf(hk, wv.w, acc[rr][3]);
                }
            }
        }
        float4* out4 = (float4*)out;
        #pragma unroll
        for (int rr = 0; rr < 4; ++rr) {
            float4 o;
            o.x = fmaxf(acc[rr][0], 0.0f);
            o.y = fmaxf(acc[rr][1], 0.0f);
            o.z = fmaxf(acc[rr][2], 0.0f);
            o.w = fmaxf(acc[rr][3], 0.0f);
            out4[(size_t)(r0 + rg * 4 + rr) * 64 + cg] = o;
        }
    }
}

// ---------------------------------------------------------------------------
extern "C" void kernel_launch(void* const* d_in, const int* in_sizes, int n_in,
                              void* d_out, int out_size, void* d_ws, size_t ws_size,
                              hipStream_t stream) {
    const float* points  = (const float*)d_in[0];
    const int*   cluster = (const int*)d_in[1];   // int32 on device (harness)
    const float* W0      = (const float*)d_in[2];
    const float* b0      = (const float*)d_in[3];
    const float* W1      = (const float*)d_in[4];
    const float* b1      = (const float*)d_in[5];
    const float* W2      = (const float*)d_in[6];
    const float* b2      = (const float*)d_in[7];
    float* out = (float*)d_out;

    float* pooled = (float*)d_ws;   // 16 MB

    k_zero<<<(NCLUST * 64 / 4) / 256, 256, 0, stream>>>((float4*)pooled);
    k_fc0_pool<<<N_PTS / 1024, 256, 0, stream>>>(points, cluster, W0, b0, pooled);
    k_mlp<<<NCLUST / 16, 256, 0, stream>>>(pooled, W1, b1, W2, b2, out);
}